// Round 1
// baseline (130.812 us; speedup 1.0000x reference)
//
#include <hip/hip_runtime.h>

#define H 8
#define T_LEN 131072
#define CHUNK_L 64
#define WARM 256
#define NCHUNK (T_LEN / CHUNK_L)
#define NS_MAX (WARM + CHUNK_L)

__device__ __forceinline__ float fast_rcp(float x) { return __builtin_amdgcn_rcpf(x); }
__device__ __forceinline__ float sigmoid_f(float x) { return fast_rcp(1.0f + __expf(-x)); }
__device__ __forceinline__ float tanh_f(float x) {
    // tanh(x) = 1 - 2/(1+exp(2x)); exp->inf => 1, exp->0 => -1 (correct saturation)
    return fmaf(-2.0f, fast_rcp(1.0f + __expf(2.0f * x)), 1.0f);
}

// One wave (64 threads) per chunk. Lanes 0..7: layer0 unit k; lanes 8..15: layer1 unit k.
// Layers pipelined: at iteration s, layer0 consumes x[t0+s], layer1 consumes y0 from s-1.
// Lanes 16..63 mirror lanes 0..15 (same values; harmless, keeps code convergent).
__global__ __launch_bounds__(64) void gru_chunk_kernel(
    const float* __restrict__ x, const float* __restrict__ h0,
    const float* __restrict__ wih0, const float* __restrict__ whh0,
    const float* __restrict__ bih0, const float* __restrict__ bhh0,
    const float* __restrict__ wih1, const float* __restrict__ whh1,
    const float* __restrict__ bih1, const float* __restrict__ bhh1,
    const float* __restrict__ wlin, const float* __restrict__ blin,
    float* __restrict__ out)
{
    const int c = blockIdx.x;
    const int tid = threadIdx.x;
    const int al = tid & 15;
    const int layer = al >> 3;
    const int k = al & 7;
    const int base8 = layer << 3;

    int t_first = c * CHUNK_L - WARM;
    if (t_first < 0) t_first = 0;
    const int tend = c * CHUNK_L + CHUNK_L;
    const int nsteps = tend - t_first;          // <= NS_MAX
    const int skip = c * CHUNK_L - t_first;     // warm-up steps to discard
    const bool true_init = (t_first == 0);      // warm-up reached t=0 -> exact

    // stage x[t_first .. tend) into LDS, +2 zero pad for the prefetch tail
    __shared__ float sx[NS_MAX + 2];
    for (int i = tid; i < nsteps; i += 64) sx[i] = x[t_first + i];
    if (tid < 2) sx[nsteps + tid] = 0.0f;
    __syncthreads();

    // per-lane weights: 3 hh rows + 3 ih rows (layer0 ih is column 0 only)
    const float* whh = layer ? whh1 : whh0;
    const float* bih = layer ? bih1 : bih0;
    const float* bhh = layer ? bhh1 : bhh0;

    float whr[8], whz[8], whn[8], wir[8], wiz[8], win[8];
#pragma unroll
    for (int e = 0; e < 8; e++) {
        whr[e] = whh[(0 + k) * 8 + e];
        whz[e] = whh[(8 + k) * 8 + e];
        whn[e] = whh[(16 + k) * 8 + e];
    }
    if (layer == 0) {
#pragma unroll
        for (int e = 0; e < 8; e++) { wir[e] = 0.0f; wiz[e] = 0.0f; win[e] = 0.0f; }
        wir[0] = wih0[0 + k];
        wiz[0] = wih0[8 + k];
        win[0] = wih0[16 + k];
    } else {
#pragma unroll
        for (int e = 0; e < 8; e++) {
            wir[e] = wih1[(0 + k) * 8 + e];
            wiz[e] = wih1[(8 + k) * 8 + e];
            win[e] = wih1[(16 + k) * 8 + e];
        }
    }
    const float br    = bih[0 + k] + bhh[0 + k];   // r: both biases fold
    const float bz    = bih[8 + k] + bhh[8 + k];   // z: both biases fold
    const float bin_n = bih[16 + k];               // n: input-side bias
    const float bhn   = bhh[16 + k];               // n: hidden-side bias (inside r*(...))

    float wl[8];
#pragma unroll
    for (int e = 0; e < 8; e++) wl[e] = wlin[e];
    const float bl = blin[0];

    // state: hL = own layer's full h (broadcast), hk = own unit's h, y0 = layer0's h (input to layer1)
    float hL[8], y0[8], hk;
    if (true_init) {
#pragma unroll
        for (int e = 0; e < 8; e++) { hL[e] = h0[base8 + e]; y0[e] = h0[e]; }
        hk = h0[base8 + k];
    } else {
#pragma unroll
        for (int e = 0; e < 8; e++) { hL[e] = 0.0f; y0[e] = 0.0f; }
        hk = 0.0f;
    }

    float xcur = sx[0];
    for (int s = 0; s <= nsteps; s++) {
        float xnext = sx[s + 1];                 // prefetch; latency hidden under compute
        float in0 = layer ? y0[0] : xcur;        // layer0 input lives in slot 0 (w[e>0]==0)

        float ghr = br, ghz = bz, ghn = bhn;
        float gxr = 0.0f, gxz = 0.0f, gxn = bin_n;
#pragma unroll
        for (int e = 0; e < 8; e++) {
            float ie = (e == 0) ? in0 : y0[e];
            ghr = fmaf(whr[e], hL[e], ghr);
            ghz = fmaf(whz[e], hL[e], ghz);
            ghn = fmaf(whn[e], hL[e], ghn);
            gxr = fmaf(wir[e], ie, gxr);
            gxz = fmaf(wiz[e], ie, gxz);
            gxn = fmaf(win[e], ie, gxn);
        }
        float r = sigmoid_f(ghr + gxr);
        float z = sigmoid_f(ghz + gxz);
        float n = tanh_f(fmaf(r, ghn, gxn));
        float hnew = fmaf(z, hk - n, n);         // (1-z)*n + z*h

        // at s==0 layer1 hasn't consumed a valid input yet -> republish its init state
        bool upd = (s > 0) || (al < 8);
        float hv = upd ? hnew : hk;
        hk = hv;
#pragma unroll
        for (int e = 0; e < 8; e++) y0[e] = __shfl(hv, e);            // new layer0 h
#pragma unroll
        for (int e = 0; e < 8; e++) hL[e] = __shfl(hv, base8 | e);    // own layer's new h

        // readout: layer1 lanes hold full h1 in hL after the update
        float ov = bl;
#pragma unroll
        for (int e = 0; e < 8; e++) ov = fmaf(wl[e], hL[e], ov);
        if (tid == 8 && s > skip) out[t_first + s - 1] = ov;

        xcur = xnext;
    }
}

extern "C" void kernel_launch(void* const* d_in, const int* in_sizes, int n_in,
                              void* d_out, int out_size, void* d_ws, size_t ws_size,
                              hipStream_t stream) {
    (void)in_sizes; (void)n_in; (void)d_ws; (void)ws_size; (void)out_size;
    const float* x    = (const float*)d_in[0];
    const float* h0   = (const float*)d_in[1];
    const float* wih0 = (const float*)d_in[2];
    const float* whh0 = (const float*)d_in[3];
    const float* bih0 = (const float*)d_in[4];
    const float* bhh0 = (const float*)d_in[5];
    const float* wih1 = (const float*)d_in[6];
    const float* whh1 = (const float*)d_in[7];
    const float* bih1 = (const float*)d_in[8];
    const float* bhh1 = (const float*)d_in[9];
    const float* wlin = (const float*)d_in[10];
    const float* blin = (const float*)d_in[11];
    float* out = (float*)d_out;

    gru_chunk_kernel<<<NCHUNK, 64, 0, stream>>>(
        x, h0, wih0, whh0, bih0, bhh0, wih1, whh1, bih1, bhh1, wlin, blin, out);
}

// Round 2
// 117.721 us; speedup vs baseline: 1.1112x; 1.1112x over previous
//
#include <hip/hip_runtime.h>

#define H 8
#define T_LEN 131072
#define CHUNK_L 64
#define WARM 208
#define NCHUNK (T_LEN / CHUNK_L)
#define NS_MAX (WARM + CHUNK_L)

__device__ __forceinline__ float fast_rcp(float x) { return __builtin_amdgcn_rcpf(x); }
__device__ __forceinline__ float sigmoid_f(float x) { return fast_rcp(1.0f + __expf(-x)); }
__device__ __forceinline__ float tanh_f(float x) {
    // tanh(x) = 1 - 2/(1+exp(2x)); saturates correctly at +-inf
    return fmaf(-2.0f, fast_rcp(1.0f + __expf(2.0f * x)), 1.0f);
}
// wave-uniform broadcast via v_readlane -> SGPR (no LDS latency)
__device__ __forceinline__ float bcast(float v, int lane) {
    return __int_as_float(__builtin_amdgcn_readlane(__float_as_int(v), lane));
}

// One wave per chunk. Lane al=tid&15: layer=al>>3, unit k=al&7; lanes 16..63 mirror.
// Layers pipelined (layer1 lags one step). State broadcast via readlane -> SGPRs;
// each lane's gate = bias + W16[0..15] . S[0..15] (+ wx * x), where S = [h0, h1].
__global__ __launch_bounds__(64) void gru_chunk_kernel(
    const float* __restrict__ x, const float* __restrict__ hinit,
    const float* __restrict__ wih0, const float* __restrict__ whh0,
    const float* __restrict__ bih0, const float* __restrict__ bhh0,
    const float* __restrict__ wih1, const float* __restrict__ whh1,
    const float* __restrict__ bih1, const float* __restrict__ bhh1,
    const float* __restrict__ wlin, const float* __restrict__ blin,
    float* __restrict__ out)
{
    const int c = blockIdx.x;
    const int tid = threadIdx.x;
    const int al = tid & 15;
    const int layer = al >> 3;
    const int k = al & 7;
    const int base8 = layer << 3;

    int t_first = c * CHUNK_L - WARM;
    if (t_first < 0) t_first = 0;
    const int tend = c * CHUNK_L + CHUNK_L;
    const int nsteps = tend - t_first;          // <= NS_MAX
    const int skip2 = (c * CHUNK_L - t_first) + 2;
    const bool true_init = (t_first == 0);

    // stage x[t_first .. tend) into LDS, +4 zero pad for tail iterations
    __shared__ float sx[NS_MAX + 4];
    for (int i = tid; i < nsteps; i += 64) sx[i] = x[t_first + i];
    if (tid < 4) sx[nsteps + tid] = 0.0f;
    __syncthreads();

    // per-lane packed weights over S = [h0(0..7), h1(0..7)]
    float Wr[16], Wz[16], Wnh[16], Wni8[8];
    float wxr, wxz, wxn, br, bz, bnh, bni;
    if (layer == 0) {
#pragma unroll
        for (int j = 0; j < 8; j++) {
            Wr[j]   = whh0[(0 + k) * H + j];
            Wz[j]   = whh0[(H + k) * H + j];
            Wnh[j]  = whh0[(2 * H + k) * H + j];
            Wr[8 + j] = 0.0f; Wz[8 + j] = 0.0f; Wnh[8 + j] = 0.0f;
            Wni8[j] = 0.0f;
        }
        wxr = wih0[k]; wxz = wih0[H + k]; wxn = wih0[2 * H + k];
        br  = bih0[k] + bhh0[k];
        bz  = bih0[H + k] + bhh0[H + k];
        bnh = bhh0[2 * H + k];
        bni = bih0[2 * H + k];
    } else {
#pragma unroll
        for (int j = 0; j < 8; j++) {
            Wr[j]     = wih1[(0 + k) * H + j];      // input side: y0 = S[0..7]
            Wz[j]     = wih1[(H + k) * H + j];
            Wni8[j]   = wih1[(2 * H + k) * H + j];
            Wr[8 + j]  = whh1[(0 + k) * H + j];     // hidden side: h1 = S[8..15]
            Wz[8 + j]  = whh1[(H + k) * H + j];
            Wnh[8 + j] = whh1[(2 * H + k) * H + j];
            Wnh[j] = 0.0f;
        }
        wxr = 0.0f; wxz = 0.0f; wxn = 0.0f;
        br  = bih1[k] + bhh1[k];
        bz  = bih1[H + k] + bhh1[H + k];
        bnh = bhh1[2 * H + k];
        bni = bih1[2 * H + k];
    }

    float wl[8];
#pragma unroll
    for (int e = 0; e < 8; e++) wl[e] = wlin[e];
    const float bl = blin[0];

    float hv;
    if (true_init) hv = hinit[base8 + k];
    else           hv = 0.0f;

    float xv = sx[0];
    const int send = nsteps + 1;
    for (int s = 0; s <= send; s++) {
        // broadcast full state to SGPRs: S[0..7]=h0, S[8..15]=h1 (post step s-1)
        float S[16];
#pragma unroll
        for (int j = 0; j < 16; j++) S[j] = bcast(hv, j);

        // readout of h1(t_first + s - 2); uniform branch, skipped during warm-up
        if (s >= skip2) {
            float ov = bl;
#pragma unroll
            for (int e = 0; e < 8; e++) ov = fmaf(wl[e], S[8 + e], ov);
            if (tid == 0) out[t_first + s - 2] = ov;
        }

        float xnext = sx[s + 1];  // prefetch (pad-zeros at the tail)

        // gates: split accumulators to halve the dependent-FMA chain
        float ar0 = br, az0 = bz, an0 = bni;
        float ar1 = 0.0f, az1 = 0.0f, ah1 = bnh;
#pragma unroll
        for (int j = 0; j < 8; j++) {
            ar0 = fmaf(Wr[j], S[j], ar0);
            az0 = fmaf(Wz[j], S[j], az0);
            an0 = fmaf(Wni8[j], S[j], an0);
            ar1 = fmaf(Wr[8 + j], S[8 + j], ar1);
            az1 = fmaf(Wz[8 + j], S[8 + j], az1);
            ah1 = fmaf(Wnh[8 + j], S[8 + j], ah1);
        }
        float anh = ah1;
        if (layer == 0) {
            // layer0's n-hidden side lives in Wnh[0..7]
            float t = 0.0f;
#pragma unroll
            for (int j = 0; j < 8; j++) t = fmaf(Wnh[j], S[j], t);
            anh = ah1 + t;
        }
        float ar = fmaf(wxr, xv, ar0 + ar1);
        float az = fmaf(wxz, xv, az0 + az1);
        float ani = fmaf(wxn, xv, an0);

        float r = sigmoid_f(ar);
        float z = sigmoid_f(az);
        float n = tanh_f(fmaf(r, anh, ani));
        float hnew = fmaf(z, hv - n, n);     // (1-z)*n + z*h

        // s==0: layer1 hasn't seen a valid input yet -> keep its init state
        bool upd = (s > 0) || (al < 8);
        hv = upd ? hnew : hv;
        xv = xnext;
    }
}

extern "C" void kernel_launch(void* const* d_in, const int* in_sizes, int n_in,
                              void* d_out, int out_size, void* d_ws, size_t ws_size,
                              hipStream_t stream) {
    (void)in_sizes; (void)n_in; (void)d_ws; (void)ws_size; (void)out_size;
    const float* x    = (const float*)d_in[0];
    const float* h0   = (const float*)d_in[1];
    const float* wih0 = (const float*)d_in[2];
    const float* whh0 = (const float*)d_in[3];
    const float* bih0 = (const float*)d_in[4];
    const float* bhh0 = (const float*)d_in[5];
    const float* wih1 = (const float*)d_in[6];
    const float* whh1 = (const float*)d_in[7];
    const float* bih1 = (const float*)d_in[8];
    const float* bhh1 = (const float*)d_in[9];
    const float* wlin = (const float*)d_in[10];
    const float* blin = (const float*)d_in[11];
    float* out = (float*)d_out;

    gru_chunk_kernel<<<NCHUNK, 64, 0, stream>>>(
        x, h0, wih0, whh0, bih0, bhh0, wih1, whh1, bih1, bhh1, wlin, blin, out);
}

// Round 3
// 76.691 us; speedup vs baseline: 1.7057x; 1.5350x over previous
//
#include <hip/hip_runtime.h>

#define H 8
#define T_LEN 131072
#define CHUNK_L 128
#define WARM 160
#define NCHUNK (T_LEN / CHUNK_L)
#define NS_MAX (WARM + CHUNK_L)

__device__ __forceinline__ float fast_rcp(float x) { return __builtin_amdgcn_rcpf(x); }
__device__ __forceinline__ float sigmoid_f(float x) { return fast_rcp(1.0f + __expf(-x)); }
__device__ __forceinline__ float tanh_f(float x) {
    // tanh(x) = 1 - 2/(1+exp(2x)); saturates correctly at +-inf
    return fmaf(-2.0f, fast_rcp(1.0f + __expf(2.0f * x)), 1.0f);
}
__device__ __forceinline__ float bcast(float v, int lane) {   // -> SGPR
    return __int_as_float(__builtin_amdgcn_readlane(__float_as_int(v), lane));
}

// One wave per chunk; 64 distinct lane roles.
// Lane = (role, layer, k): role 0:r 1:z 2:n-input 3:n-hidden; unit sub = layer*8+k.
// Each lane: one 16-long dot over SGPR state S=[h0(0..7), h1(0..7)] (+ wx*x).
// Combine: 4 ds_bpermute gather (a_r,a_z,a_ni,a_nh) for own unit -> all lanes
// redundantly compute h_new(sub) -> readlane rebroadcast. Layers pipelined
// (layer1 lags one step), identical math to the verified round-1/2 scheme.
__global__ __launch_bounds__(64, 1) void gru_chunk_kernel(
    const float* __restrict__ x, const float* __restrict__ hinit,
    const float* __restrict__ wih0, const float* __restrict__ whh0,
    const float* __restrict__ bih0, const float* __restrict__ bhh0,
    const float* __restrict__ wih1, const float* __restrict__ whh1,
    const float* __restrict__ bih1, const float* __restrict__ bhh1,
    const float* __restrict__ wlin, const float* __restrict__ blin,
    float* __restrict__ out)
{
    const int c = blockIdx.x;
    const int tid = threadIdx.x;
    const int sub = tid & 15;
    const int role = tid >> 4;
    const int layer = sub >> 3;
    const int k = sub & 7;

    int t_first = c * CHUNK_L - WARM;
    if (t_first < 0) t_first = 0;
    const int tend = c * CHUNK_L + CHUNK_L;
    const int nsteps = tend - t_first;           // <= NS_MAX
    const int skip2 = (c * CHUNK_L - t_first) + 2;
    const bool true_init = (t_first == 0);

    // stage x[t_first..tend) into LDS, +4 zero pad for tail iterations
    __shared__ float sx[NS_MAX + 4];
    for (int i = tid; i < nsteps; i += 64) sx[i] = x[t_first + i];
    if (tid < 4) sx[nsteps + tid] = 0.0f;
    __syncthreads();

    // per-lane packed weight vector over S (16 floats), scalar-x weight, bias
    float W[16];
#pragma unroll
    for (int j = 0; j < 16; j++) W[j] = 0.0f;
    float wx = 0.0f, bias;

    if (role == 0) {            // r gate
        if (layer == 0) {
#pragma unroll
            for (int j = 0; j < 8; j++) W[j] = whh0[k * H + j];
            wx = wih0[k];
            bias = bih0[k] + bhh0[k];
        } else {
#pragma unroll
            for (int j = 0; j < 8; j++) {
                W[j]     = wih1[k * H + j];      // input side: y0 = S[0..7]
                W[8 + j] = whh1[k * H + j];      // hidden side: h1 = S[8..15]
            }
            bias = bih1[k] + bhh1[k];
        }
    } else if (role == 1) {     // z gate
        const int row = H + k;
        if (layer == 0) {
#pragma unroll
            for (int j = 0; j < 8; j++) W[j] = whh0[row * H + j];
            wx = wih0[row];
            bias = bih0[row] + bhh0[row];
        } else {
#pragma unroll
            for (int j = 0; j < 8; j++) {
                W[j]     = wih1[row * H + j];
                W[8 + j] = whh1[row * H + j];
            }
            bias = bih1[row] + bhh1[row];
        }
    } else if (role == 2) {     // n gate, input side
        const int row = 2 * H + k;
        if (layer == 0) {
            wx = wih0[row];                      // input is scalar x
            bias = bih0[row];
        } else {
#pragma unroll
            for (int j = 0; j < 8; j++) W[j] = wih1[row * H + j];
            bias = bih1[row];
        }
    } else {                    // n gate, hidden side
        const int row = 2 * H + k;
        if (layer == 0) {
#pragma unroll
            for (int j = 0; j < 8; j++) W[j] = whh0[row * H + j];
            bias = bhh0[row];
        } else {
#pragma unroll
            for (int j = 0; j < 8; j++) W[8 + j] = whh1[row * H + j];
            bias = bhh1[row];
        }
    }

    float wl[8];
#pragma unroll
    for (int e = 0; e < 8; e++) wl[e] = wlin[e];
    const float bl = blin[0];

    // state of own unit (mirrored on all 4 role-lanes of that unit)
    float hv = true_init ? hinit[layer * H + k] : 0.0f;

    float xv = sx[0];
    const int send = nsteps + 1;
    for (int s = 0; s <= send; s++) {
        // broadcast state to SGPRs: S[0..7]=h0, S[8..15]=h1 (post iteration s-1)
        float S[16];
#pragma unroll
        for (int j = 0; j < 16; j++) S[j] = bcast(hv, j);

        // readout of y1(t_first+s-2); uniform branch, skipped in warm-up
        if (s >= skip2) {
            float ov = bl;
#pragma unroll
            for (int e = 0; e < 8; e++) ov = fmaf(wl[e], S[8 + e], ov);
            if (tid == 0) out[t_first + s - 2] = ov;
        }

        float xnext = sx[s + 1];   // prefetch (zero pad at the tail)

        // own dot product: split accumulators to shorten the dep chain
        float a0 = bias, a1 = 0.0f;
#pragma unroll
        for (int j = 0; j < 8; j++) {
            a0 = fmaf(W[j], S[j], a0);
            a1 = fmaf(W[8 + j], S[8 + j], a1);
        }
        float a = fmaf(wx, xv, a0 + a1);

        // gather the 4 partials of own unit (addresses loop-invariant)
        float ar  = __shfl(a, sub);
        float az  = __shfl(a, 16 + sub);
        float ani = __shfl(a, 32 + sub);
        float anh = __shfl(a, 48 + sub);

        float r = sigmoid_f(ar);
        float z = sigmoid_f(az);
        float n = tanh_f(fmaf(r, anh, ani));
        float hnew = fmaf(z, hv - n, n);         // (1-z)*n + z*h

        // s==0: layer1 hasn't consumed a valid y0 yet -> keep its init state
        hv = (s == 0 && sub >= 8) ? hv : hnew;
        xv = xnext;
    }
}

extern "C" void kernel_launch(void* const* d_in, const int* in_sizes, int n_in,
                              void* d_out, int out_size, void* d_ws, size_t ws_size,
                              hipStream_t stream) {
    (void)in_sizes; (void)n_in; (void)d_ws; (void)ws_size; (void)out_size;
    const float* x    = (const float*)d_in[0];
    const float* h0   = (const float*)d_in[1];
    const float* wih0 = (const float*)d_in[2];
    const float* whh0 = (const float*)d_in[3];
    const float* bih0 = (const float*)d_in[4];
    const float* bhh0 = (const float*)d_in[5];
    const float* wih1 = (const float*)d_in[6];
    const float* whh1 = (const float*)d_in[7];
    const float* bih1 = (const float*)d_in[8];
    const float* bhh1 = (const float*)d_in[9];
    const float* wlin = (const float*)d_in[10];
    const float* blin = (const float*)d_in[11];
    float* out = (float*)d_out;

    gru_chunk_kernel<<<NCHUNK, 64, 0, stream>>>(
        x, h0, wih0, whh0, bih0, bhh0, wih1, whh1, bih1, bhh1, wlin, blin, out);
}

// Round 4
// 51.882 us; speedup vs baseline: 2.5213x; 1.4782x over previous
//
#include <hip/hip_runtime.h>

#define H 8
#define T_LEN 131072
#define CHUNK_L 128
#define WARM 128
#define NCHUNK (T_LEN / CHUNK_L)
#define NS_MAX (WARM + CHUNK_L)

__device__ __forceinline__ float fast_rcp(float x) { return __builtin_amdgcn_rcpf(x); }
__device__ __forceinline__ float sigmoid_f(float x) { return fast_rcp(1.0f + __expf(-x)); }
__device__ __forceinline__ float tanh_f(float x) {
    // tanh(x) = 1 - 2/(1+exp(2x)); saturates correctly at +-inf
    return fmaf(-2.0f, fast_rcp(1.0f + __expf(2.0f * x)), 1.0f);
}
__device__ __forceinline__ float bcast(float v, int lane) {   // v_readlane -> SGPR
    return __int_as_float(__builtin_amdgcn_readlane(__float_as_int(v), lane));
}
// broadcast quad-lane Q's value to all 4 lanes of each quad (DPP quad_perm; VALU pipe,
// ~4 cyc — replaces the ds_bpermute (~120 cyc DS latency) on the serial chain)
template<int Q>
__device__ __forceinline__ float quad_bcast(float v) {
    return __int_as_float(__builtin_amdgcn_update_dpp(
        0, __float_as_int(v), Q * 0x55, 0xf, 0xf, true));
}

// One wave per chunk; 64 distinct lane roles, quad-major:
// lane = unit*4 + role; unit = layer*8 + k (0..15); role 0:r 1:z 2:n-input 3:n-hidden.
// Each lane: one 16-long dot over SGPR state S=[h0(0..7), h1(0..7)] (+ wx*x).
// Combine: 4 DPP quad_perm broadcasts -> every lane computes h_new(unit) redundantly
// -> readlane rebroadcast. Layers pipelined (layer1 lags one step) — identical math
// to the verified round-1..3 scheme.
__global__ __launch_bounds__(64, 1) void gru_chunk_kernel(
    const float* __restrict__ x, const float* __restrict__ hinit,
    const float* __restrict__ wih0, const float* __restrict__ whh0,
    const float* __restrict__ bih0, const float* __restrict__ bhh0,
    const float* __restrict__ wih1, const float* __restrict__ whh1,
    const float* __restrict__ bih1, const float* __restrict__ bhh1,
    const float* __restrict__ wlin, const float* __restrict__ blin,
    float* __restrict__ out)
{
    const int c = blockIdx.x;
    const int tid = threadIdx.x;
    const int sub = tid >> 2;        // unit 0..15
    const int role = tid & 3;        // r / z / n-input / n-hidden
    const int layer = sub >> 3;
    const int k = sub & 7;

    int t_first = c * CHUNK_L - WARM;
    if (t_first < 0) t_first = 0;
    const int tend = c * CHUNK_L + CHUNK_L;
    const int nsteps = tend - t_first;            // <= NS_MAX
    const int skip2 = (c * CHUNK_L - t_first) + 2;
    const bool true_init = (t_first == 0);

    // stage x[t_first..tend) into LDS, +4 zero pad for the prefetch tail
    __shared__ float sx[NS_MAX + 4];
    for (int i = tid; i < nsteps; i += 64) sx[i] = x[t_first + i];
    if (tid < 4) sx[nsteps + tid] = 0.0f;
    __syncthreads();

    // per-lane packed weight vector over S (16 floats), scalar-x weight, bias
    float W[16];
#pragma unroll
    for (int j = 0; j < 16; j++) W[j] = 0.0f;
    float wx = 0.0f, bias;

    if (role == 0) {            // r gate
        if (layer == 0) {
#pragma unroll
            for (int j = 0; j < 8; j++) W[j] = whh0[k * H + j];
            wx = wih0[k];
            bias = bih0[k] + bhh0[k];
        } else {
#pragma unroll
            for (int j = 0; j < 8; j++) {
                W[j]     = wih1[k * H + j];       // input side: y0 = S[0..7]
                W[8 + j] = whh1[k * H + j];       // hidden side: h1 = S[8..15]
            }
            bias = bih1[k] + bhh1[k];
        }
    } else if (role == 1) {     // z gate
        const int row = H + k;
        if (layer == 0) {
#pragma unroll
            for (int j = 0; j < 8; j++) W[j] = whh0[row * H + j];
            wx = wih0[row];
            bias = bih0[row] + bhh0[row];
        } else {
#pragma unroll
            for (int j = 0; j < 8; j++) {
                W[j]     = wih1[row * H + j];
                W[8 + j] = whh1[row * H + j];
            }
            bias = bih1[row] + bhh1[row];
        }
    } else if (role == 2) {     // n gate, input side
        const int row = 2 * H + k;
        if (layer == 0) {
            wx = wih0[row];                       // input is scalar x
            bias = bih0[row];
        } else {
#pragma unroll
            for (int j = 0; j < 8; j++) W[j] = wih1[row * H + j];
            bias = bih1[row];
        }
    } else {                    // n gate, hidden side
        const int row = 2 * H + k;
        if (layer == 0) {
#pragma unroll
            for (int j = 0; j < 8; j++) W[j] = whh0[row * H + j];
            bias = bhh0[row];
        } else {
#pragma unroll
            for (int j = 0; j < 8; j++) W[8 + j] = whh1[row * H + j];
            bias = bhh1[row];
        }
    }

    float wl[8];
#pragma unroll
    for (int e = 0; e < 8; e++) wl[e] = wlin[e];
    const float bl = blin[0];

    // own unit's state (mirrored on its 4 role-lanes)
    float hv = true_init ? hinit[layer * H + k] : 0.0f;
    float xv = sx[0];
    int s = 0;

#define GRU_STEP(GUARD, DO_OUT)                                              \
    do {                                                                     \
        float S[16];                                                         \
        _Pragma("unroll")                                                    \
        for (int j = 0; j < 16; j++) S[j] = bcast(hv, 4 * j);                \
        if (DO_OUT) {                                                        \
            float ov = bl;                                                   \
            _Pragma("unroll")                                                \
            for (int e = 0; e < 8; e++) ov = fmaf(wl[e], S[8 + e], ov);      \
            if (tid == 0) out[t_first + s - 2] = ov;                         \
        }                                                                    \
        float xnext = sx[s + 1];                                             \
        float a0 = bias, a1 = 0.0f;                                          \
        _Pragma("unroll")                                                    \
        for (int j = 0; j < 8; j++) {                                        \
            a0 = fmaf(W[j], S[j], a0);                                       \
            a1 = fmaf(W[8 + j], S[8 + j], a1);                               \
        }                                                                    \
        float a = fmaf(wx, xv, a0 + a1);                                     \
        float ar  = quad_bcast<0>(a);                                        \
        float az  = quad_bcast<1>(a);                                        \
        float ani = quad_bcast<2>(a);                                        \
        float anh = quad_bcast<3>(a);                                        \
        float r = sigmoid_f(ar);                                             \
        float z = sigmoid_f(az);                                             \
        float n = tanh_f(fmaf(r, anh, ani));                                 \
        float hnew = fmaf(z, hv - n, n);                                     \
        if (GUARD) hv = (sub >= 8) ? hv : hnew; else hv = hnew;              \
        xv = xnext;                                                          \
    } while (0)

    // s == 0: layer1 keeps its init state (its y0 input is not valid yet)
    GRU_STEP(true, false);
    s++;
    // warm-up: no readout
    for (; s < skip2; s++) GRU_STEP(false, false);
    // steady state: readout of y1(t_first + s - 2) each step
    const int send = nsteps + 1;
    for (; s <= send; s++) GRU_STEP(false, true);

#undef GRU_STEP
}

extern "C" void kernel_launch(void* const* d_in, const int* in_sizes, int n_in,
                              void* d_out, int out_size, void* d_ws, size_t ws_size,
                              hipStream_t stream) {
    (void)in_sizes; (void)n_in; (void)d_ws; (void)ws_size; (void)out_size;
    const float* x    = (const float*)d_in[0];
    const float* h0   = (const float*)d_in[1];
    const float* wih0 = (const float*)d_in[2];
    const float* whh0 = (const float*)d_in[3];
    const float* bih0 = (const float*)d_in[4];
    const float* bhh0 = (const float*)d_in[5];
    const float* wih1 = (const float*)d_in[6];
    const float* whh1 = (const float*)d_in[7];
    const float* bih1 = (const float*)d_in[8];
    const float* bhh1 = (const float*)d_in[9];
    const float* wlin = (const float*)d_in[10];
    const float* blin = (const float*)d_in[11];
    float* out = (float*)d_out;

    gru_chunk_kernel<<<NCHUNK, 64, 0, stream>>>(
        x, h0, wih0, whh0, bih0, bhh0, wih1, whh1, bih1, bhh1, wlin, blin, out);
}